// Round 1
// baseline (4912.244 us; speedup 1.0000x reference)
//
#include <hip/hip_runtime.h>

// VQ nearest-neighbor: argmin_k ||c_k||^2 - 2 x_n . c_k
// N=32768 rows, K=8192 codes, D=512, fp32 in, int32 indices out.
//
// Round 1: fp32 tiled GEMM + fused argmin. 128x128 tile, BD=16,
// 8x16 micro-tile, 128 thr/block, K-split 4 + combine pass.
// fp32 needed: bf16 dot error (~3e-6) vs min top-2 gap (~2e-8 over all rows)
// would flip ~100 argmins -> fail index-absmax check.

#define D_DIM 512
#define BM 128
#define BN 128
#define BD 16

__global__ __launch_bounds__(256) void cbsqr_kernel(const float* __restrict__ cb,
                                                    float* __restrict__ out, int K) {
    int gtid = blockIdx.x * blockDim.x + threadIdx.x;
    int w = gtid >> 6;          // one wave per code row
    int lane = gtid & 63;
    if (w >= K) return;
    const float4* r4 = (const float4*)(cb + (size_t)w * D_DIM) + lane * 2;
    float4 u = r4[0], v = r4[1];
    float s = u.x*u.x + u.y*u.y + u.z*u.z + u.w*u.w
            + v.x*v.x + v.y*v.y + v.z*v.z + v.w*v.w;
#pragma unroll
    for (int off = 32; off; off >>= 1) s += __shfl_xor(s, off);
    if (lane == 0) out[w] = s;
}

// rows handled by thread: i<4 -> ty*4+i ; else 64+ty*4+(i-4)
// codes handled by thread: j -> (j>>2)*32 + tx*4 + (j&3)   (ascending in j)
__global__ __launch_bounds__(128, 2) void vq_kernel(
        const float* __restrict__ X, const float* __restrict__ CB,
        const float* __restrict__ cbs,
        float* __restrict__ pd, int* __restrict__ pi,
        int* __restrict__ out, int N, int K, int nsplit) {

    __shared__ float As[BD][BM + 4];   // [d][row], stride 132 floats (16B aligned)
    __shared__ float Bs[BD][BN + 4];   // [d][code]

    const int tid = threadIdx.x;
    const int tx = tid & 7;        // code dim (8)
    const int ty = tid >> 3;       // row dim (16)
    const int rowBase = blockIdx.x * BM;
    const int split = blockIdx.y;
    const int kPer = K / nsplit;
    const int c0 = split * kPer, c1 = c0 + kPer;

    const int ldRow = tid >> 2;        // 0..31
    const int ldCol = (tid & 3) * 4;   // 0,4,8,12

    float bestD[8];
    int bestI[8];
#pragma unroll
    for (int i = 0; i < 8; ++i) { bestD[i] = 3.4e38f; bestI[i] = 0; }

    for (int ct = c0; ct < c1; ct += BN) {
        float acc[8][16];
#pragma unroll
        for (int i = 0; i < 8; ++i)
#pragma unroll
            for (int j = 0; j < 16; ++j) acc[i][j] = 0.f;

        for (int dt = 0; dt < D_DIM; dt += BD) {
            // stage A,B transposed: [d][row]. 4 passes x (2 float4 loads, 8 LDS writes)
#pragma unroll
            for (int p = 0; p < 4; ++p) {
                int r = ldRow + p * 32;
                float4 av = *(const float4*)&X[(size_t)(rowBase + r) * D_DIM + dt + ldCol];
                float4 bv = *(const float4*)&CB[(size_t)(ct + r) * D_DIM + dt + ldCol];
                As[ldCol + 0][r] = av.x; As[ldCol + 1][r] = av.y;
                As[ldCol + 2][r] = av.z; As[ldCol + 3][r] = av.w;
                Bs[ldCol + 0][r] = bv.x; Bs[ldCol + 1][r] = bv.y;
                Bs[ldCol + 2][r] = bv.z; Bs[ldCol + 3][r] = bv.w;
            }
            __syncthreads();
#pragma unroll
            for (int d = 0; d < BD; ++d) {
                float4 a0 = *(const float4*)&As[d][ty * 4];
                float4 a1 = *(const float4*)&As[d][64 + ty * 4];
                float4 b0 = *(const float4*)&Bs[d][ 0 + tx * 4];
                float4 b1 = *(const float4*)&Bs[d][32 + tx * 4];
                float4 b2 = *(const float4*)&Bs[d][64 + tx * 4];
                float4 b3 = *(const float4*)&Bs[d][96 + tx * 4];
                float a[8] = {a0.x,a0.y,a0.z,a0.w,a1.x,a1.y,a1.z,a1.w};
                float b[16] = {b0.x,b0.y,b0.z,b0.w, b1.x,b1.y,b1.z,b1.w,
                               b2.x,b2.y,b2.z,b2.w, b3.x,b3.y,b3.z,b3.w};
#pragma unroll
                for (int i = 0; i < 8; ++i)
#pragma unroll
                    for (int j = 0; j < 16; ++j)
                        acc[i][j] = fmaf(a[i], b[j], acc[i][j]);
            }
            __syncthreads();
        }

        // fused argmin epilogue for this code tile (ascending code order)
#pragma unroll
        for (int j = 0; j < 16; ++j) {
            int code = ct + (j >> 2) * 32 + tx * 4 + (j & 3);
            float c2 = cbs[code];
#pragma unroll
            for (int i = 0; i < 8; ++i) {
                float dist = fmaf(-2.f, acc[i][j], c2);
                if (dist < bestD[i]) { bestD[i] = dist; bestI[i] = code; }
            }
        }
    }

    // reduce across the 8 tx lanes sharing the same rows (consecutive lanes)
#pragma unroll
    for (int i = 0; i < 8; ++i) {
        float bd = bestD[i]; int bi = bestI[i];
#pragma unroll
        for (int off = 1; off < 8; off <<= 1) {
            float od = __shfl_xor(bd, off);
            int   oi = __shfl_xor(bi, off);
            if (od < bd || (od == bd && oi < bi)) { bd = od; bi = oi; }
        }
        if (tx == 0) {
            int row = rowBase + ((i < 4) ? ty * 4 + i : 64 + ty * 4 + (i - 4));
            if (nsplit == 1) out[row] = bi;
            else {
                pd[(size_t)row * nsplit + split] = bd;
                pi[(size_t)row * nsplit + split] = bi;
            }
        }
    }
}

__global__ __launch_bounds__(256) void combine_kernel(
        const float* __restrict__ pd, const int* __restrict__ pi,
        int* __restrict__ out, int N, int S) {
    int r = blockIdx.x * blockDim.x + threadIdx.x;
    if (r >= N) return;
    float bd = pd[(size_t)r * S];
    int bi = pi[(size_t)r * S];
    for (int s = 1; s < S; ++s) {
        float d = pd[(size_t)r * S + s];
        int i = pi[(size_t)r * S + s];
        if (d < bd || (d == bd && i < bi)) { bd = d; bi = i; }
    }
    out[r] = bi;
}

extern "C" void kernel_launch(void* const* d_in, const int* in_sizes, int n_in,
                              void* d_out, int out_size, void* d_ws, size_t ws_size,
                              hipStream_t stream) {
    const float* X  = (const float*)d_in[0];
    const float* CB = (const float*)d_in[1];
    int N = in_sizes[0] / D_DIM;
    int K = in_sizes[1] / D_DIM;
    int* out = (int*)d_out;

    float* cbs = (float*)d_ws;
    size_t off = (size_t)K * sizeof(float);

    int nsplit = 4;
    while (nsplit > 1 &&
           (ws_size < off + (size_t)N * nsplit * (sizeof(float) + sizeof(int)) ||
            (K % (nsplit * BN)) != 0))
        nsplit >>= 1;

    float* pd = (float*)((char*)d_ws + off);
    int*   pi = (int*)((char*)d_ws + off + (size_t)N * nsplit * sizeof(float));

    cbsqr_kernel<<<(K + 3) / 4, 256, 0, stream>>>(CB, cbs, K);

    dim3 grid(N / BM, nsplit);
    vq_kernel<<<grid, 128, 0, stream>>>(X, CB, cbs, pd, pi, out, N, K, nsplit);

    if (nsplit > 1)
        combine_kernel<<<(N + 255) / 256, 256, 0, stream>>>(pd, pi, out, N, nsplit);
}

// Round 2
// 1810.657 us; speedup vs baseline: 2.7130x; 2.7130x over previous
//
#include <hip/hip_runtime.h>

// VQ nearest-neighbor: argmin_k ||c_k||^2 - 2 x_n . c_k
// N=32768 rows, K=8192 codes, D=512, fp32 in, int32 indices out.
//
// Round 2: bf16-split MFMA (3 GEMM terms: xh*ch + xh*cl + xl*ch) with
// top-2 gap tracking + exact fp32 refinement of near-tie rows.
// m97-style 128x128 tile, BK=32, global_load_lds width 16, 4 waves.

#define D_DIM 512
#define EPS_GAP 1.5e-6f

typedef __attribute__((ext_vector_type(8))) short short8;
typedef __attribute__((ext_vector_type(4))) float f32x4;
typedef __attribute__((ext_vector_type(4))) unsigned short us4;

__device__ __forceinline__ unsigned short f2bf(float x) {
    unsigned u = __float_as_uint(x);
    u += 0x7fffu + ((u >> 16) & 1u);          // RNE
    return (unsigned short)(u >> 16);
}
__device__ __forceinline__ float bf2f(unsigned short h) {
    return __uint_as_float(((unsigned)h) << 16);
}

__device__ __forceinline__ void gload_lds16(const void* g, void* l) {
    __builtin_amdgcn_global_load_lds(
        (const __attribute__((address_space(1))) unsigned int*)g,
        (__attribute__((address_space(3))) unsigned int*)l, 16, 0, 0);
}

// ---- pass 0a: split fp32 -> (hi, lo) bf16 ----
__global__ __launch_bounds__(256) void split_kernel(const float* __restrict__ src,
                                                    unsigned short* __restrict__ hi,
                                                    unsigned short* __restrict__ lo,
                                                    int n4) {
    int i = blockIdx.x * blockDim.x + threadIdx.x;
    int stride = gridDim.x * blockDim.x;
    for (; i < n4; i += stride) {
        float4 v = ((const float4*)src)[i];
        us4 h, l;
        h.x = f2bf(v.x); l.x = f2bf(v.x - bf2f(h.x));
        h.y = f2bf(v.y); l.y = f2bf(v.y - bf2f(h.y));
        h.z = f2bf(v.z); l.z = f2bf(v.z - bf2f(h.z));
        h.w = f2bf(v.w); l.w = f2bf(v.w - bf2f(h.w));
        ((us4*)hi)[i] = h;
        ((us4*)lo)[i] = l;
    }
}

// ---- pass 0b: ||c||^2 (fp32), also zero the flag counter ----
__global__ __launch_bounds__(256) void cbsqr_kernel(const float* __restrict__ cb,
                                                    float* __restrict__ out,
                                                    int* __restrict__ cnt, int K) {
    if (blockIdx.x == 0 && threadIdx.x == 0) *cnt = 0;
    int gtid = blockIdx.x * blockDim.x + threadIdx.x;
    int w = gtid >> 6;
    int lane = gtid & 63;
    if (w >= K) return;
    const float4* r4 = (const float4*)(cb + (size_t)w * D_DIM) + lane * 2;
    float4 u = r4[0], v = r4[1];
    float s = u.x*u.x + u.y*u.y + u.z*u.z + u.w*u.w
            + v.x*v.x + v.y*v.y + v.z*v.z + v.w*v.w;
#pragma unroll
    for (int off = 32; off; off >>= 1) s += __shfl_xor(s, off);
    if (lane == 0) out[w] = s;
}

// ---- pass 1: MFMA approx dists + per-(row,colblock) top-2 partials ----
// grid (N/128, K/128), 256 threads (4 waves in 2x2).
__global__ __launch_bounds__(256) void vq_mfma_kernel(
        const unsigned short* __restrict__ Xh, const unsigned short* __restrict__ Xl,
        const unsigned short* __restrict__ Ch, const unsigned short* __restrict__ Cl,
        const float* __restrict__ cbs,
        float* __restrict__ pd1, int* __restrict__ pi1, float* __restrict__ pd2,
        int N) {

    __shared__ unsigned short As[128 * 32];
    __shared__ unsigned short Bs[128 * 32];
    __shared__ float redD1[2][128];
    __shared__ int   redI1[2][128];
    __shared__ float redD2[2][128];

    const int tid  = threadIdx.x;
    const int lane = tid & 63;
    const int wid  = tid >> 6;
    const int wr   = wid >> 1;       // row half (0/1)
    const int wc   = wid & 1;        // col half (0/1)
    const int rowBase  = blockIdx.x * 128;
    const int codeBase = blockIdx.y * 128;

    const int l4 = lane >> 2;        // 0..15 (staging row within 16)
    const int lk = lane & 3;         // staging k-chunk (8 elems)

    // per-lane global element offsets (row-major [row][512])
    const size_t gA0 = (size_t)(rowBase  + wid * 32 + l4) * D_DIM + lk * 8;
    const size_t gB0 = (size_t)(codeBase + wid * 32 + l4) * D_DIM + lk * 8;
    unsigned short* lA = &As[wid * 1024 + lane * 8];   // lane*16B within wave's 2KB
    unsigned short* lB = &Bs[wid * 1024 + lane * 8];

    f32x4 acc[4][4];
#pragma unroll
    for (int m = 0; m < 4; ++m)
#pragma unroll
        for (int n = 0; n < 4; ++n) acc[m][n] = (f32x4){0.f, 0.f, 0.f, 0.f};

    const unsigned short* Aterm[3] = {Xh, Xh, Xl};
    const unsigned short* Bterm[3] = {Ch, Cl, Ch};

    const int kOff = (lane >> 4) * 8;          // fragment k base (elems)
    const int rA = wr * 64 + (lane & 15);
    const int rB = wc * 64 + (lane & 15);

    for (int t = 0; t < 3; ++t) {
        const unsigned short* Ap = Aterm[t];
        const unsigned short* Bp = Bterm[t];
        for (int kt = 0; kt < 16; ++kt) {
            const int ko = kt * 32;
            gload_lds16(Ap + gA0 + ko,        lA);
            gload_lds16(Ap + gA0 + 8192 + ko, lA + 512);   // +16 rows
            gload_lds16(Bp + gB0 + ko,        lB);
            gload_lds16(Bp + gB0 + 8192 + ko, lB + 512);
            __syncthreads();   // drains vmcnt -> tiles ready

            short8 av[4], bv[4];
#pragma unroll
            for (int m = 0; m < 4; ++m)
                av[m] = *(const short8*)&As[(rA + m * 16) * 32 + kOff];
#pragma unroll
            for (int n = 0; n < 4; ++n)
                bv[n] = *(const short8*)&Bs[(rB + n * 16) * 32 + kOff];
#pragma unroll
            for (int m = 0; m < 4; ++m)
#pragma unroll
                for (int n = 0; n < 4; ++n)
                    acc[m][n] = __builtin_amdgcn_mfma_f32_16x16x32_bf16(
                        av[m], bv[n], acc[m][n], 0, 0, 0);
            __syncthreads();   // protect LDS before next stage
        }
    }

    // ---- epilogue: dist = cbs - 2*dot; top-2 (value,index) per row ----
    float c2[4];
#pragma unroll
    for (int n = 0; n < 4; ++n)
        c2[n] = cbs[codeBase + wc * 64 + n * 16 + (lane & 15)];

#pragma unroll
    for (int m = 0; m < 4; ++m) {
#pragma unroll
        for (int r = 0; r < 4; ++r) {
            float d1 = 3.4e38f, d2 = 3.4e38f;
            int i1 = 0x7fffffff;
#pragma unroll
            for (int n = 0; n < 4; ++n) {
                float dist = fmaf(-2.f, acc[m][n][r], c2[n]);
                int code = codeBase + wc * 64 + n * 16 + (lane & 15);
                bool lt = dist < d1;
                d2 = lt ? d1 : fminf(d2, dist);
                i1 = lt ? code : i1;
                d1 = lt ? dist : d1;
            }
            // reduce across the 16 lanes of this C-column group
#pragma unroll
            for (int off = 1; off < 16; off <<= 1) {
                float od1 = __shfl_xor(d1, off);
                int   oi1 = __shfl_xor(i1, off);
                float od2 = __shfl_xor(d2, off);
                bool bwin = (od1 < d1) || (od1 == d1 && oi1 < i1);
                if (bwin) { d2 = fminf(od2, d1); d1 = od1; i1 = oi1; }
                else      { d2 = fminf(d2, od1); }
            }
            if ((lane & 15) == 0) {
                int rowInBlk = wr * 64 + m * 16 + (lane >> 4) * 4 + r;
                redD1[wc][rowInBlk] = d1;
                redI1[wc][rowInBlk] = i1;
                redD2[wc][rowInBlk] = d2;
            }
        }
    }
    __syncthreads();
    if (tid < 128) {
        float d1 = redD1[0][tid]; int i1 = redI1[0][tid]; float d2 = redD2[0][tid];
        float od1 = redD1[1][tid]; int oi1 = redI1[1][tid]; float od2 = redD2[1][tid];
        bool bwin = (od1 < d1) || (od1 == d1 && oi1 < i1);
        if (bwin) { d2 = fminf(od2, d1); d1 = od1; i1 = oi1; }
        else      { d2 = fminf(d2, od1); }
        size_t p = (size_t)blockIdx.y * N + (rowBase + tid);   // [colblock][row]
        pd1[p] = d1; pi1[p] = i1; pd2[p] = d2;
    }
}

// ---- pass 2: merge col-block partials, emit index + near-tie flags ----
__global__ __launch_bounds__(256) void combine2_kernel(
        const float* __restrict__ pd1, const int* __restrict__ pi1,
        const float* __restrict__ pd2,
        int* __restrict__ out, int* __restrict__ flags, int* __restrict__ cnt,
        int N, int S) {
    int row = blockIdx.x * blockDim.x + threadIdx.x;
    if (row >= N) return;
    float d1 = pd1[row]; int i1 = pi1[row]; float d2 = pd2[row];
    for (int s = 1; s < S; ++s) {
        size_t p = (size_t)s * N + row;
        float od1 = pd1[p]; int oi1 = pi1[p]; float od2 = pd2[p];
        bool bwin = (od1 < d1) || (od1 == d1 && oi1 < i1);
        if (bwin) { d2 = fminf(od2, d1); d1 = od1; i1 = oi1; }
        else      { d2 = fminf(d2, od1); }
    }
    out[row] = i1;
    if (d2 - d1 < EPS_GAP) {
        int f = atomicAdd(cnt, 1);
        flags[f] = row;
    }
}

// ---- pass 3: exact fp32 re-solve of flagged rows ----
__global__ __launch_bounds__(256) void refine_kernel(
        const float* __restrict__ X, const float* __restrict__ CB,
        const float* __restrict__ cbs,
        const int* __restrict__ flags, const int* __restrict__ cnt,
        int* __restrict__ out, int K) {
    __shared__ float xs[D_DIM];
    __shared__ float rD[4];
    __shared__ int   rI[4];
    const int nf = *cnt;
    for (int f = blockIdx.x; f < nf; f += gridDim.x) {
        const int row = flags[f];
        __syncthreads();   // protect xs reuse across iterations
        for (int i = threadIdx.x; i < D_DIM; i += 256)
            xs[i] = X[(size_t)row * D_DIM + i];
        __syncthreads();
        float bd = 3.4e38f; int bi = 0x7fffffff;
        for (int c = threadIdx.x; c < K; c += 256) {
            const float4* cp = (const float4*)(CB + (size_t)c * D_DIM);
            float dot = 0.f;
#pragma unroll 8
            for (int d = 0; d < D_DIM / 4; ++d) {
                float4 cv = cp[d];
                float4 xv = *(const float4*)&xs[d * 4];
                dot = fmaf(xv.x, cv.x, dot);
                dot = fmaf(xv.y, cv.y, dot);
                dot = fmaf(xv.z, cv.z, dot);
                dot = fmaf(xv.w, cv.w, dot);
            }
            float dist = fmaf(-2.f, dot, cbs[c]);
            if (dist < bd) { bd = dist; bi = c; }
        }
#pragma unroll
        for (int off = 1; off < 64; off <<= 1) {
            float od = __shfl_xor(bd, off);
            int   oi = __shfl_xor(bi, off);
            if (od < bd || (od == bd && oi < bi)) { bd = od; bi = oi; }
        }
        if ((threadIdx.x & 63) == 0) { rD[threadIdx.x >> 6] = bd; rI[threadIdx.x >> 6] = bi; }
        __syncthreads();
        if (threadIdx.x == 0) {
            for (int w = 1; w < 4; ++w)
                if (rD[w] < bd || (rD[w] == bd && rI[w] < bi)) { bd = rD[w]; bi = rI[w]; }
            out[row] = bi;
        }
    }
}

// ================= fp32 fallback (round-1, spill-relaxed) =================
#define BM 128
#define BN 128
#define BD 16

__global__ __launch_bounds__(128) void vq_fp32_kernel(
        const float* __restrict__ X, const float* __restrict__ CB,
        const float* __restrict__ cbs,
        float* __restrict__ pd, int* __restrict__ pi,
        int* __restrict__ out, int N, int K, int nsplit) {

    __shared__ float As[BD][BM + 4];
    __shared__ float Bs[BD][BN + 4];

    const int tid = threadIdx.x;
    const int tx = tid & 7;
    const int ty = tid >> 3;
    const int rowBase = blockIdx.x * BM;
    const int split = blockIdx.y;
    const int kPer = K / nsplit;
    const int c0 = split * kPer, c1 = c0 + kPer;
    const int ldRow = tid >> 2;
    const int ldCol = (tid & 3) * 4;

    float bestD[8]; int bestI[8];
#pragma unroll
    for (int i = 0; i < 8; ++i) { bestD[i] = 3.4e38f; bestI[i] = 0; }

    for (int ct = c0; ct < c1; ct += BN) {
        float acc[8][16];
#pragma unroll
        for (int i = 0; i < 8; ++i)
#pragma unroll
            for (int j = 0; j < 16; ++j) acc[i][j] = 0.f;

        for (int dt = 0; dt < D_DIM; dt += BD) {
#pragma unroll
            for (int p = 0; p < 4; ++p) {
                int r = ldRow + p * 32;
                float4 av = *(const float4*)&X[(size_t)(rowBase + r) * D_DIM + dt + ldCol];
                float4 bv = *(const float4*)&CB[(size_t)(ct + r) * D_DIM + dt + ldCol];
                As[ldCol + 0][r] = av.x; As[ldCol + 1][r] = av.y;
                As[ldCol + 2][r] = av.z; As[ldCol + 3][r] = av.w;
                Bs[ldCol + 0][r] = bv.x; Bs[ldCol + 1][r] = bv.y;
                Bs[ldCol + 2][r] = bv.z; Bs[ldCol + 3][r] = bv.w;
            }
            __syncthreads();
#pragma unroll
            for (int d = 0; d < BD; ++d) {
                float4 a0 = *(const float4*)&As[d][ty * 4];
                float4 a1 = *(const float4*)&As[d][64 + ty * 4];
                float4 b0 = *(const float4*)&Bs[d][ 0 + tx * 4];
                float4 b1 = *(const float4*)&Bs[d][32 + tx * 4];
                float4 b2 = *(const float4*)&Bs[d][64 + tx * 4];
                float4 b3 = *(const float4*)&Bs[d][96 + tx * 4];
                float a[8] = {a0.x,a0.y,a0.z,a0.w,a1.x,a1.y,a1.z,a1.w};
                float b[16] = {b0.x,b0.y,b0.z,b0.w, b1.x,b1.y,b1.z,b1.w,
                               b2.x,b2.y,b2.z,b2.w, b3.x,b3.y,b3.z,b3.w};
#pragma unroll
                for (int i = 0; i < 8; ++i)
#pragma unroll
                    for (int j = 0; j < 16; ++j)
                        acc[i][j] = fmaf(a[i], b[j], acc[i][j]);
            }
            __syncthreads();
        }
#pragma unroll
        for (int j = 0; j < 16; ++j) {
            int code = ct + (j >> 2) * 32 + tx * 4 + (j & 3);
            float c2v = cbs[code];
#pragma unroll
            for (int i = 0; i < 8; ++i) {
                float dist = fmaf(-2.f, acc[i][j], c2v);
                if (dist < bestD[i]) { bestD[i] = dist; bestI[i] = code; }
            }
        }
    }
#pragma unroll
    for (int i = 0; i < 8; ++i) {
        float bd = bestD[i]; int bi = bestI[i];
#pragma unroll
        for (int off = 1; off < 8; off <<= 1) {
            float od = __shfl_xor(bd, off);
            int   oi = __shfl_xor(bi, off);
            if (od < bd || (od == bd && oi < bi)) { bd = od; bi = oi; }
        }
        if (tx == 0) {
            int row = rowBase + ((i < 4) ? ty * 4 + i : 64 + ty * 4 + (i - 4));
            if (nsplit == 1) out[row] = bi;
            else {
                pd[(size_t)row * nsplit + split] = bd;
                pi[(size_t)row * nsplit + split] = bi;
            }
        }
    }
}

__global__ __launch_bounds__(256) void combine_fp32_kernel(
        const float* __restrict__ pd, const int* __restrict__ pi,
        int* __restrict__ out, int N, int S) {
    int r = blockIdx.x * blockDim.x + threadIdx.x;
    if (r >= N) return;
    float bd = pd[(size_t)r * S];
    int bi = pi[(size_t)r * S];
    for (int s = 1; s < S; ++s) {
        float d = pd[(size_t)r * S + s];
        int i = pi[(size_t)r * S + s];
        if (d < bd || (d == bd && i < bi)) { bd = d; bi = i; }
    }
    out[r] = bi;
}

// =========================== launcher ===========================
extern "C" void kernel_launch(void* const* d_in, const int* in_sizes, int n_in,
                              void* d_out, int out_size, void* d_ws, size_t ws_size,
                              hipStream_t stream) {
    const float* X  = (const float*)d_in[0];
    const float* CB = (const float*)d_in[1];
    const int N = in_sizes[0] / D_DIM;
    const int K = in_sizes[1] / D_DIM;
    int* out = (int*)d_out;

    const int S = K / 128;   // col blocks

    // workspace layout (256B aligned chunks)
    size_t o = 0;
    auto take = [&](size_t bytes) { size_t r = o; o += (bytes + 255) & ~(size_t)255; return r; };
    size_t oCbs = take((size_t)K * 4);
    size_t oXh  = take((size_t)N * D_DIM * 2);
    size_t oXl  = take((size_t)N * D_DIM * 2);
    size_t oCh  = take((size_t)K * D_DIM * 2);
    size_t oCl  = take((size_t)K * D_DIM * 2);
    size_t oPd1 = take((size_t)N * S * 4);
    size_t oPi1 = take((size_t)N * S * 4);
    size_t oPd2 = take((size_t)N * S * 4);
    size_t oFlg = take((size_t)N * 4);
    size_t oCnt = take(256);
    const size_t need = o;

    char* ws = (char*)d_ws;
    float* cbs = (float*)(ws + oCbs);

    if (ws_size >= need && (N % 128) == 0 && (K % 128) == 0) {
        unsigned short* Xh = (unsigned short*)(ws + oXh);
        unsigned short* Xl = (unsigned short*)(ws + oXl);
        unsigned short* Ch = (unsigned short*)(ws + oCh);
        unsigned short* Cl = (unsigned short*)(ws + oCl);
        float* pd1 = (float*)(ws + oPd1);
        int*   pi1 = (int*)(ws + oPi1);
        float* pd2 = (float*)(ws + oPd2);
        int* flags = (int*)(ws + oFlg);
        int* cnt   = (int*)(ws + oCnt);

        split_kernel<<<4096, 256, 0, stream>>>(X,  Xh, Xl, N * D_DIM / 4);
        split_kernel<<<1024, 256, 0, stream>>>(CB, Ch, Cl, K * D_DIM / 4);
        cbsqr_kernel<<<(K + 3) / 4, 256, 0, stream>>>(CB, cbs, cnt, K);

        dim3 grid(N / 128, K / 128);
        vq_mfma_kernel<<<grid, 256, 0, stream>>>(Xh, Xl, Ch, Cl, cbs,
                                                 pd1, pi1, pd2, N);
        combine2_kernel<<<(N + 255) / 256, 256, 0, stream>>>(pd1, pi1, pd2,
                                                             out, flags, cnt, N, S);
        refine_kernel<<<256, 256, 0, stream>>>(X, CB, cbs, flags, cnt, out, K);
    } else {
        // fp32 fallback
        int* cnt = (int*)(ws + oCbs + ((size_t)K * 4 + 255 & ~(size_t)255)); // unused slot
        (void)cnt;
        size_t base = ((size_t)K * 4 + 255) & ~(size_t)255;
        int nsplit = 4;
        while (nsplit > 1 &&
               (ws_size < base + (size_t)N * nsplit * 8 || (K % (nsplit * BN)) != 0))
            nsplit >>= 1;
        float* pd = (float*)(ws + base);
        int*   pi = (int*)(ws + base + (size_t)N * nsplit * 4);
        int dummy;
        cbsqr_kernel<<<(K + 3) / 4, 256, 0, stream>>>(CB, cbs, (int*)&dummy == nullptr ? nullptr : (int*)(ws + base), K);
        // note: counter write goes into pd[0] slot; pd is fully rewritten by
        // vq_fp32_kernel before combine reads it, so this is harmless.
        dim3 grid(N / BM, nsplit);
        vq_fp32_kernel<<<grid, 128, 0, stream>>>(X, CB, cbs, pd, pi, out, N, K, nsplit);
        if (nsplit > 1)
            combine_fp32_kernel<<<(N + 255) / 256, 256, 0, stream>>>(pd, pi, out, N, nsplit);
    }
}

// Round 3
// 1341.696 us; speedup vs baseline: 3.6612x; 1.3495x over previous
//
#include <hip/hip_runtime.h>

// VQ nearest-neighbor: argmin_k ||c_k||^2 - 2 x_n . c_k
// N=32768 rows, K=8192 codes, D=512, fp32 in, int32 indices out.
//
// Round 3: fused bf16-split MFMA (xh*ch + xl*ch + xh*cl in ONE staging pass),
// LDS XOR-swizzle (chunk ^= (row>>1)&3) via pre-swizzled global_load_lds
// source, K-split 8 with 8 col-tiles per block and register top-2,
// XCD-affine block decode, batched exact fp32 refine of near-tie rows.

#define D_DIM 512
#define EPS_GAP 1.5e-6f
#define KSPLIT 8
#define RPB 4

typedef __attribute__((ext_vector_type(8))) short short8;
typedef __attribute__((ext_vector_type(4))) float f32x4;
typedef __attribute__((ext_vector_type(4))) unsigned short us4;

__device__ __forceinline__ unsigned short f2bf(float x) {
    unsigned u = __float_as_uint(x);
    u += 0x7fffu + ((u >> 16) & 1u);          // RNE
    return (unsigned short)(u >> 16);
}
__device__ __forceinline__ float bf2f(unsigned short h) {
    return __uint_as_float(((unsigned)h) << 16);
}

__device__ __forceinline__ void gload_lds16(const void* g, void* l) {
    __builtin_amdgcn_global_load_lds(
        (const __attribute__((address_space(1))) unsigned int*)g,
        (__attribute__((address_space(3))) unsigned int*)l, 16, 0, 0);
}

// ---- pass 0a: split fp32 -> (hi, lo) bf16 ----
__global__ __launch_bounds__(256) void split_kernel(const float* __restrict__ src,
                                                    unsigned short* __restrict__ hi,
                                                    unsigned short* __restrict__ lo,
                                                    int n4) {
    int i = blockIdx.x * blockDim.x + threadIdx.x;
    int stride = gridDim.x * blockDim.x;
    for (; i < n4; i += stride) {
        float4 v = ((const float4*)src)[i];
        us4 h, l;
        h.x = f2bf(v.x); l.x = f2bf(v.x - bf2f(h.x));
        h.y = f2bf(v.y); l.y = f2bf(v.y - bf2f(h.y));
        h.z = f2bf(v.z); l.z = f2bf(v.z - bf2f(h.z));
        h.w = f2bf(v.w); l.w = f2bf(v.w - bf2f(h.w));
        ((us4*)hi)[i] = h;
        ((us4*)lo)[i] = l;
    }
}

// ---- pass 0b: ||c||^2 (fp32), also zero the flag counter ----
__global__ __launch_bounds__(256) void cbsqr_kernel(const float* __restrict__ cb,
                                                    float* __restrict__ out,
                                                    int* __restrict__ cnt, int K) {
    if (blockIdx.x == 0 && threadIdx.x == 0 && cnt) *cnt = 0;
    int gtid = blockIdx.x * blockDim.x + threadIdx.x;
    int w = gtid >> 6;
    int lane = gtid & 63;
    if (w >= K) return;
    const float4* r4 = (const float4*)(cb + (size_t)w * D_DIM) + lane * 2;
    float4 u = r4[0], v = r4[1];
    float s = u.x*u.x + u.y*u.y + u.z*u.z + u.w*u.w
            + v.x*v.x + v.y*v.y + v.z*v.z + v.w*v.w;
#pragma unroll
    for (int off = 32; off; off >>= 1) s += __shfl_xor(s, off);
    if (lane == 0) out[w] = s;
}

// ---- pass 1: fused MFMA dists + register top-2, 8 col-tiles per block ----
// grid = (N/128)*KSPLIT blocks, 256 threads (4 waves 2x2).
// bid&7 = split (XCD-affine: each XCD keeps its codebook slice in L2).
__global__ __launch_bounds__(256, 2) void vq_mfma_kernel(
        const unsigned short* __restrict__ Xh, const unsigned short* __restrict__ Xl,
        const unsigned short* __restrict__ Ch, const unsigned short* __restrict__ Cl,
        const float* __restrict__ cbs,
        float* __restrict__ pd1, int* __restrict__ pi1, float* __restrict__ pd2,
        int N, int K) {

    __shared__ unsigned short Ah[128 * 32], Al[128 * 32];
    __shared__ unsigned short Bh[128 * 32], Bl[128 * 32];
    __shared__ float redD1[2][128];
    __shared__ int   redI1[2][128];
    __shared__ float redD2[2][128];

    const int tid  = threadIdx.x;
    const int lane = tid & 63;
    const int wid  = tid >> 6;
    const int wr   = wid >> 1;       // row half
    const int wc   = wid & 1;        // col half
    const int bid  = blockIdx.x;
    const int split    = bid & (KSPLIT - 1);
    const int rowBase  = (bid >> 3) * 128;
    const int kPerSplit = K / KSPLIT;
    const int splitBase = split * kPerSplit;
    const int NTCOL = kPerSplit / 128;

    // staging: lane l covers LDS row wid*32+(l>>2), 16B chunk p=l&3.
    // swizzle s(r)=(r>>1)&3 -> source chunk = p ^ s = (l&3)^((l>>3)&3).
    const int l4  = lane >> 2;
    const int swz = ((lane & 3) ^ ((lane >> 3) & 3)) * 8;
    const size_t gA0 = (size_t)(rowBase + wid * 32 + l4) * D_DIM + swz;
    const size_t gB0 = (size_t)(wid * 32 + l4) * D_DIM + swz;
    unsigned short* lAh = &Ah[wid * 1024 + lane * 8];
    unsigned short* lAl = &Al[wid * 1024 + lane * 8];
    unsigned short* lBh = &Bh[wid * 1024 + lane * 8];
    unsigned short* lBl = &Bl[wid * 1024 + lane * 8];

    // read side: row rA+16m, want chunk c=lane>>4 -> read pos c^s(rA),
    // s(rA+16m) = (lane>>1)&3 for all m.
    const int rA = wr * 64 + (lane & 15);
    const int rB = wc * 64 + (lane & 15);
    const int kSwz = (((lane >> 4) ^ ((lane >> 1) & 3))) * 8;

    float bd1[4][4], bd2[4][4];
    int   bi1[4][4];
#pragma unroll
    for (int m = 0; m < 4; ++m)
#pragma unroll
        for (int r = 0; r < 4; ++r) {
            bd1[m][r] = 3.4e38f; bd2[m][r] = 3.4e38f; bi1[m][r] = 0x7fffffff;
        }

    for (int ct = 0; ct < NTCOL; ++ct) {
        const int codeBase = splitBase + ct * 128;
        const unsigned short* ChB = Ch + (size_t)codeBase * D_DIM;
        const unsigned short* ClB = Cl + (size_t)codeBase * D_DIM;

        f32x4 acc[4][4];
#pragma unroll
        for (int m = 0; m < 4; ++m)
#pragma unroll
            for (int n = 0; n < 4; ++n) acc[m][n] = (f32x4){0.f, 0.f, 0.f, 0.f};

        for (int kt = 0; kt < D_DIM / 32; ++kt) {
            const int ko = kt * 32;
            gload_lds16(Xh + gA0 + ko,               lAh);
            gload_lds16(Xh + gA0 + ko + 16 * D_DIM, lAh + 512);
            gload_lds16(Xl + gA0 + ko,               lAl);
            gload_lds16(Xl + gA0 + ko + 16 * D_DIM, lAl + 512);
            gload_lds16(ChB + gB0 + ko,               lBh);
            gload_lds16(ChB + gB0 + ko + 16 * D_DIM, lBh + 512);
            gload_lds16(ClB + gB0 + ko,               lBl);
            gload_lds16(ClB + gB0 + ko + 16 * D_DIM, lBl + 512);
            __syncthreads();   // drain vmcnt -> tiles visible

            short8 bvh[4], bvl[4];
#pragma unroll
            for (int n = 0; n < 4; ++n) {
                bvh[n] = *(const short8*)&Bh[(rB + n * 16) * 32 + kSwz];
                bvl[n] = *(const short8*)&Bl[(rB + n * 16) * 32 + kSwz];
            }
#pragma unroll
            for (int m = 0; m < 4; ++m) {
                short8 avh = *(const short8*)&Ah[(rA + m * 16) * 32 + kSwz];
                short8 avl = *(const short8*)&Al[(rA + m * 16) * 32 + kSwz];
#pragma unroll
                for (int n = 0; n < 4; ++n) {
                    acc[m][n] = __builtin_amdgcn_mfma_f32_16x16x32_bf16(
                        avh, bvh[n], acc[m][n], 0, 0, 0);
                    acc[m][n] = __builtin_amdgcn_mfma_f32_16x16x32_bf16(
                        avl, bvh[n], acc[m][n], 0, 0, 0);
                    acc[m][n] = __builtin_amdgcn_mfma_f32_16x16x32_bf16(
                        avh, bvl[n], acc[m][n], 0, 0, 0);
                }
            }
            __syncthreads();   // protect LDS before next staging
        }

        // per-tile top-2 update (registers only; codes ascend -> first-min ties)
        float c2[4]; int cc[4];
#pragma unroll
        for (int n = 0; n < 4; ++n) {
            cc[n] = codeBase + wc * 64 + n * 16 + (lane & 15);
            c2[n] = cbs[cc[n]];
        }
#pragma unroll
        for (int m = 0; m < 4; ++m)
#pragma unroll
            for (int r = 0; r < 4; ++r)
#pragma unroll
                for (int n = 0; n < 4; ++n) {
                    float dist = fmaf(-2.f, acc[m][n][r], c2[n]);
                    bool lt = dist < bd1[m][r];
                    bd2[m][r] = lt ? bd1[m][r] : fminf(bd2[m][r], dist);
                    bi1[m][r] = lt ? cc[n] : bi1[m][r];
                    bd1[m][r] = lt ? dist : bd1[m][r];
                }
    }

    // final cross-lane reduce (once per block)
#pragma unroll
    for (int m = 0; m < 4; ++m)
#pragma unroll
        for (int r = 0; r < 4; ++r) {
            float d1 = bd1[m][r]; int i1 = bi1[m][r]; float d2 = bd2[m][r];
#pragma unroll
            for (int off = 1; off < 16; off <<= 1) {
                float od1 = __shfl_xor(d1, off);
                int   oi1 = __shfl_xor(i1, off);
                float od2 = __shfl_xor(d2, off);
                bool bwin = (od1 < d1) || (od1 == d1 && oi1 < i1);
                if (bwin) { d2 = fminf(od2, d1); d1 = od1; i1 = oi1; }
                else      { d2 = fminf(d2, od1); }
            }
            if ((lane & 15) == 0) {
                int rowInBlk = wr * 64 + m * 16 + (lane >> 4) * 4 + r;
                redD1[wc][rowInBlk] = d1;
                redI1[wc][rowInBlk] = i1;
                redD2[wc][rowInBlk] = d2;
            }
        }
    __syncthreads();
    if (tid < 128) {
        float d1 = redD1[0][tid]; int i1 = redI1[0][tid]; float d2 = redD2[0][tid];
        float od1 = redD1[1][tid]; int oi1 = redI1[1][tid]; float od2 = redD2[1][tid];
        bool bwin = (od1 < d1) || (od1 == d1 && oi1 < i1);
        if (bwin) { d2 = fminf(od2, d1); d1 = od1; i1 = oi1; }
        else      { d2 = fminf(d2, od1); }
        size_t p = (size_t)split * N + (rowBase + tid);
        pd1[p] = d1; pi1[p] = i1; pd2[p] = d2;
    }
}

// ---- pass 2: merge split partials, emit index + near-tie flags ----
__global__ __launch_bounds__(256) void combine2_kernel(
        const float* __restrict__ pd1, const int* __restrict__ pi1,
        const float* __restrict__ pd2,
        int* __restrict__ out, int* __restrict__ flags, int* __restrict__ cnt,
        int N, int S) {
    int row = blockIdx.x * blockDim.x + threadIdx.x;
    if (row >= N) return;
    float d1 = pd1[row]; int i1 = pi1[row]; float d2 = pd2[row];
    for (int s = 1; s < S; ++s) {
        size_t p = (size_t)s * N + row;
        float od1 = pd1[p]; int oi1 = pi1[p]; float od2 = pd2[p];
        bool bwin = (od1 < d1) || (od1 == d1 && oi1 < i1);
        if (bwin) { d2 = fminf(od2, d1); d1 = od1; i1 = oi1; }
        else      { d2 = fminf(d2, od1); }
    }
    out[row] = i1;
    if (d2 - d1 < EPS_GAP) {
        int f = atomicAdd(cnt, 1);
        flags[f] = row;
    }
}

// ---- pass 3: exact fp32 re-solve of flagged rows (RPB rows/block) ----
__global__ __launch_bounds__(256) void refine_kernel(
        const float* __restrict__ X, const float* __restrict__ CB,
        const float* __restrict__ cbs,
        const int* __restrict__ flags, const int* __restrict__ cnt,
        int* __restrict__ out, int K) {
    __shared__ float xs[RPB][D_DIM];
    __shared__ float rD[RPB][4];
    __shared__ int   rI[RPB][4];
    const int nf = *cnt;
    for (int f0 = blockIdx.x * RPB; f0 < nf; f0 += gridDim.x * RPB) {
        const int nr = min(RPB, nf - f0);
        __syncthreads();   // protect xs reuse across iterations
        for (int i = threadIdx.x; i < nr * D_DIM; i += 256)
            xs[i >> 9][i & 511] = X[(size_t)flags[f0 + (i >> 9)] * D_DIM + (i & 511)];
        __syncthreads();
        float bd[RPB]; int bi[RPB];
#pragma unroll
        for (int rr = 0; rr < RPB; ++rr) { bd[rr] = 3.4e38f; bi[rr] = 0x7fffffff; }
        for (int c = threadIdx.x; c < K; c += 256) {
            const float4* cp = (const float4*)(CB + (size_t)c * D_DIM);
            float dot[RPB] = {0.f, 0.f, 0.f, 0.f};
#pragma unroll 4
            for (int d = 0; d < D_DIM / 4; ++d) {
                float4 cv = cp[d];
#pragma unroll
                for (int rr = 0; rr < RPB; ++rr) {
                    float4 xv = *(const float4*)&xs[rr][d * 4];
                    dot[rr] = fmaf(xv.x, cv.x, dot[rr]);
                    dot[rr] = fmaf(xv.y, cv.y, dot[rr]);
                    dot[rr] = fmaf(xv.z, cv.z, dot[rr]);
                    dot[rr] = fmaf(xv.w, cv.w, dot[rr]);
                }
            }
            float c2v = cbs[c];
#pragma unroll
            for (int rr = 0; rr < RPB; ++rr) {
                float dist = fmaf(-2.f, dot[rr], c2v);
                if (dist < bd[rr]) { bd[rr] = dist; bi[rr] = c; }
            }
        }
#pragma unroll
        for (int rr = 0; rr < RPB; ++rr) {
            float d = bd[rr]; int i = bi[rr];
#pragma unroll
            for (int off = 1; off < 64; off <<= 1) {
                float od = __shfl_xor(d, off);
                int   oi = __shfl_xor(i, off);
                if (od < d || (od == d && oi < i)) { d = od; i = oi; }
            }
            if ((threadIdx.x & 63) == 0) {
                rD[rr][threadIdx.x >> 6] = d;
                rI[rr][threadIdx.x >> 6] = i;
            }
        }
        __syncthreads();
        if (threadIdx.x < RPB && (int)threadIdx.x < nr) {
            int rr = threadIdx.x;
            float d = rD[rr][0]; int i = rI[rr][0];
            for (int w = 1; w < 4; ++w)
                if (rD[rr][w] < d || (rD[rr][w] == d && rI[rr][w] < i)) {
                    d = rD[rr][w]; i = rI[rr][w];
                }
            out[flags[f0 + rr]] = i;
        }
    }
}

// ================= fp32 fallback (generic shapes) =================
#define BM 128
#define BN 128
#define BD 16

__global__ __launch_bounds__(128) void vq_fp32_kernel(
        const float* __restrict__ X, const float* __restrict__ CB,
        const float* __restrict__ cbs,
        float* __restrict__ pd, int* __restrict__ pi,
        int* __restrict__ out, int N, int K, int nsplit) {

    __shared__ float As[BD][BM + 4];
    __shared__ float Bs[BD][BN + 4];

    const int tid = threadIdx.x;
    const int tx = tid & 7;
    const int ty = tid >> 3;
    const int rowBase = blockIdx.x * BM;
    const int split = blockIdx.y;
    const int kPer = K / nsplit;
    const int c0 = split * kPer, c1 = c0 + kPer;
    const int ldRow = tid >> 2;
    const int ldCol = (tid & 3) * 4;

    float bestD[8]; int bestI[8];
#pragma unroll
    for (int i = 0; i < 8; ++i) { bestD[i] = 3.4e38f; bestI[i] = 0; }

    for (int ct = c0; ct < c1; ct += BN) {
        float acc[8][16];
#pragma unroll
        for (int i = 0; i < 8; ++i)
#pragma unroll
            for (int j = 0; j < 16; ++j) acc[i][j] = 0.f;

        for (int dt = 0; dt < D_DIM; dt += BD) {
#pragma unroll
            for (int p = 0; p < 4; ++p) {
                int r = ldRow + p * 32;
                float4 av = *(const float4*)&X[(size_t)(rowBase + r) * D_DIM + dt + ldCol];
                float4 bv = *(const float4*)&CB[(size_t)(ct + r) * D_DIM + dt + ldCol];
                As[ldCol + 0][r] = av.x; As[ldCol + 1][r] = av.y;
                As[ldCol + 2][r] = av.z; As[ldCol + 3][r] = av.w;
                Bs[ldCol + 0][r] = bv.x; Bs[ldCol + 1][r] = bv.y;
                Bs[ldCol + 2][r] = bv.z; Bs[ldCol + 3][r] = bv.w;
            }
            __syncthreads();
#pragma unroll
            for (int d = 0; d < BD; ++d) {
                float4 a0 = *(const float4*)&As[d][ty * 4];
                float4 a1 = *(const float4*)&As[d][64 + ty * 4];
                float4 b0 = *(const float4*)&Bs[d][ 0 + tx * 4];
                float4 b1 = *(const float4*)&Bs[d][32 + tx * 4];
                float4 b2 = *(const float4*)&Bs[d][64 + tx * 4];
                float4 b3 = *(const float4*)&Bs[d][96 + tx * 4];
                float a[8] = {a0.x,a0.y,a0.z,a0.w,a1.x,a1.y,a1.z,a1.w};
                float b[16] = {b0.x,b0.y,b0.z,b0.w, b1.x,b1.y,b1.z,b1.w,
                               b2.x,b2.y,b2.z,b2.w, b3.x,b3.y,b3.z,b3.w};
#pragma unroll
                for (int i = 0; i < 8; ++i)
#pragma unroll
                    for (int j = 0; j < 16; ++j)
                        acc[i][j] = fmaf(a[i], b[j], acc[i][j]);
            }
            __syncthreads();
        }
#pragma unroll
        for (int j = 0; j < 16; ++j) {
            int code = ct + (j >> 2) * 32 + tx * 4 + (j & 3);
            float c2v = cbs[code];
#pragma unroll
            for (int i = 0; i < 8; ++i) {
                float dist = fmaf(-2.f, acc[i][j], c2v);
                if (dist < bestD[i]) { bestD[i] = dist; bestI[i] = code; }
            }
        }
    }
#pragma unroll
    for (int i = 0; i < 8; ++i) {
        float bd = bestD[i]; int bi = bestI[i];
#pragma unroll
        for (int off = 1; off < 8; off <<= 1) {
            float od = __shfl_xor(bd, off);
            int   oi = __shfl_xor(bi, off);
            if (od < bd || (od == bd && oi < bi)) { bd = od; bi = oi; }
        }
        if (tx == 0) {
            int row = rowBase + ((i < 4) ? ty * 4 + i : 64 + ty * 4 + (i - 4));
            if (nsplit == 1) out[row] = bi;
            else {
                pd[(size_t)row * nsplit + split] = bd;
                pi[(size_t)row * nsplit + split] = bi;
            }
        }
    }
}

__global__ __launch_bounds__(256) void combine_fp32_kernel(
        const float* __restrict__ pd, const int* __restrict__ pi,
        int* __restrict__ out, int N, int S) {
    int r = blockIdx.x * blockDim.x + threadIdx.x;
    if (r >= N) return;
    float bd = pd[(size_t)r * S];
    int bi = pi[(size_t)r * S];
    for (int s = 1; s < S; ++s) {
        float d = pd[(size_t)r * S + s];
        int i = pi[(size_t)r * S + s];
        if (d < bd || (d == bd && i < bi)) { bd = d; bi = i; }
    }
    out[r] = bi;
}

// =========================== launcher ===========================
extern "C" void kernel_launch(void* const* d_in, const int* in_sizes, int n_in,
                              void* d_out, int out_size, void* d_ws, size_t ws_size,
                              hipStream_t stream) {
    const float* X  = (const float*)d_in[0];
    const float* CB = (const float*)d_in[1];
    const int N = in_sizes[0] / D_DIM;
    const int K = in_sizes[1] / D_DIM;
    int* out = (int*)d_out;

    size_t o = 0;
    auto take = [&](size_t bytes) { size_t r = o; o += (bytes + 255) & ~(size_t)255; return r; };
    size_t oCbs = take((size_t)K * 4);
    size_t oXh  = take((size_t)N * D_DIM * 2);
    size_t oXl  = take((size_t)N * D_DIM * 2);
    size_t oCh  = take((size_t)K * D_DIM * 2);
    size_t oCl  = take((size_t)K * D_DIM * 2);
    size_t oPd1 = take((size_t)N * KSPLIT * 4);
    size_t oPi1 = take((size_t)N * KSPLIT * 4);
    size_t oPd2 = take((size_t)N * KSPLIT * 4);
    size_t oFlg = take((size_t)N * 4);
    size_t oCnt = take(256);
    const size_t need = o;

    char* ws = (char*)d_ws;
    float* cbs = (float*)(ws + oCbs);

    if (ws_size >= need && (N % 128) == 0 && (K % (128 * KSPLIT)) == 0) {
        unsigned short* Xh = (unsigned short*)(ws + oXh);
        unsigned short* Xl = (unsigned short*)(ws + oXl);
        unsigned short* Ch = (unsigned short*)(ws + oCh);
        unsigned short* Cl = (unsigned short*)(ws + oCl);
        float* pd1 = (float*)(ws + oPd1);
        int*   pi1 = (int*)(ws + oPi1);
        float* pd2 = (float*)(ws + oPd2);
        int* flags = (int*)(ws + oFlg);
        int* cnt   = (int*)(ws + oCnt);

        split_kernel<<<4096, 256, 0, stream>>>(X,  Xh, Xl, N * D_DIM / 4);
        split_kernel<<<1024, 256, 0, stream>>>(CB, Ch, Cl, K * D_DIM / 4);
        cbsqr_kernel<<<(K + 3) / 4, 256, 0, stream>>>(CB, cbs, cnt, K);

        vq_mfma_kernel<<<(N / 128) * KSPLIT, 256, 0, stream>>>(
            Xh, Xl, Ch, Cl, cbs, pd1, pi1, pd2, N, K);
        combine2_kernel<<<(N + 255) / 256, 256, 0, stream>>>(pd1, pi1, pd2,
                                                             out, flags, cnt, N, KSPLIT);
        refine_kernel<<<256, 256, 0, stream>>>(X, CB, cbs, flags, cnt, out, K);
    } else {
        size_t base = ((size_t)K * 4 + 255) & ~(size_t)255;
        int nsplit = 4;
        while (nsplit > 1 &&
               (ws_size < base + (size_t)N * nsplit * 8 || (K % (nsplit * BN)) != 0))
            nsplit >>= 1;
        float* pd = (float*)(ws + base);
        int*   pi = (int*)(ws + base + (size_t)N * nsplit * 4);
        cbsqr_kernel<<<(K + 3) / 4, 256, 0, stream>>>(CB, cbs, nullptr, K);
        dim3 grid(N / BM, nsplit);
        vq_fp32_kernel<<<grid, 128, 0, stream>>>(X, CB, cbs, pd, pi, out, N, K, nsplit);
        if (nsplit > 1)
            combine_fp32_kernel<<<(N + 255) / 256, 256, 0, stream>>>(pd, pi, out, N, nsplit);
    }
}